// Round 1
// 3902.853 us; speedup vs baseline: 1.7395x; 1.7395x over previous
//
#include <hip/hip_runtime.h>
#include <cstdint>

// Problem constants
static constexpr int BATCH  = 32;
static constexpr int TLEN   = 2048;
static constexpr int DIN    = 256;    // input dim
static constexpr int HDIM   = 512;    // hidden dim
static constexpr int G4     = 2048;   // 4*HDIM (gate cols, order i,f,g,o)
static constexpr int NSLICE = 8;      // blocks per batch
static constexpr int HCB    = 64;     // h-cols per block
static constexpr int CPB    = 256;    // gate-cols per block (4 * HCB)
static constexpr int NTHR   = 512;    // 8 waves
static constexpr int NWAVE  = 8;
static constexpr int KL     = 96;     // k-values per wave
static constexpr int KL2    = 48;     // packed f16x2 (u32) per wave
static constexpr int NBLK   = BATCH * NSLICE;  // 256 blocks = 1/CU

typedef _Float16 h2v __attribute__((ext_vector_type(2)));

__device__ __forceinline__ uint32_t pack_f16x2(float a, float b) {
    h2v v;
    v[0] = (_Float16)a;   // scalar f32->f16 converts RTN
    v[1] = (_Float16)b;
    return __builtin_bit_cast(uint32_t, v);
}

__device__ __forceinline__ float dot2f(uint32_t w, uint32_t u, float acc) {
#if __has_builtin(__builtin_amdgcn_fdot2)
    return __builtin_amdgcn_fdot2(__builtin_bit_cast(h2v, w),
                                  __builtin_bit_cast(h2v, u), acc, false);
#else
    h2v a = __builtin_bit_cast(h2v, w);
    h2v b = __builtin_bit_cast(h2v, u);
    return acc + (float)a[0] * (float)b[0] + (float)a[1] * (float)b[1];
#endif
}

__device__ __forceinline__ float sigmoidf_(float x) {
    return 1.0f / (1.0f + __expf(-x));
}
// tanh via exp; handles +-inf saturation correctly
__device__ __forceinline__ float tanhf_(float x) {
    return 1.0f - 2.0f / (1.0f + __expf(2.0f * x));
}

// Persistent LSTM: one launch runs all 2048 timesteps.
// grid = 32 batches x 8 slices, block = 512 threads, 1 block/CU.
//
// R2 redesign: TAGGED-WORD h exchange. The R1 scheme (h stores -> vmcnt(0)
// -> flag store -> reader polls flag -> reader loads h) serializes THREE
// fabric/MALL round trips per step; rocprof showed VALUBusy 22% with the
// dot phase only ~0.4us of a 3.3us step -- pure sync latency.
// Now each h element is published as ONE u32: (tag=t+1)<<16 | f16(h).
// Readers poll the data words directly (relaxed agent atomics, which on
// gfx950 bypass the non-coherent per-XCD caches to the fabric coherence
// point); a matching tag means the payload is already in hand. No flags,
// no writer-side vmcnt fence, no post-detect fetch.
//
// Each wave polls/stages ONLY its own 96-k chunk (one u64 atomic load per
// lane covers a packed f16 pair), writes its private LDS chunk, and starts
// its dot immediately -- x-only waves (k<256) never poll at all.
// One __syncthreads per step; gp partials are parity double-buffered.
//
// Race-freedom sketch (2-deep h parity buffer + gp parity):
//  - tag T lives in parity T&1; word tag T overwritten by T+2 only after
//    the owner slice finished step T+1, which required tag-(T+1) words from
//    ALL slices, which required every block's UPDATE(T), which is after
//    every block's barrier(T), which is after all polls for tag T passed.
//  - any wave's iteration-(t+2) write of gp[t&1] is program-ordered after
//    barrier(t+1), which requires wave 0's arrival, which follows
//    UPDATE(t)'s gp[t&1] reads.
__global__ __launch_bounds__(NTHR, 2) void lstm_persist(
    const float* __restrict__ x, const int* __restrict__ lens,
    const float* __restrict__ Wi, const float* __restrict__ Wh,
    const float* __restrict__ bias, float* __restrict__ out,
    uint32_t* __restrict__ hT)   // [2][BATCH][HDIM] u32 tagged f16
{
    // Block -> (batch, slice); keeps a batch's 8 blocks on one XCD under the
    // blockIdx%8 round-robin heuristic (perf only, not correctness).
    const int bid = blockIdx.x;
    const int xcd = bid & 7;
    const int t8  = bid >> 3;          // 0..31
    const int b   = xcd * 4 + (t8 & 3);
    const int s   = t8 >> 2;           // slice 0..7

    const int tid = threadIdx.x;
    const int w   = tid >> 6;          // wave 0..7 -> k-chunk [96w, 96w+96)
    const int l   = tid & 63;          // lane -> gate-cols {4l..4l+3}

    __shared__ __align__(16) uint32_t u_lds[NWAVE][KL2];  // per-wave chunk, f16x2
    __shared__ float gp[2][NWAVE][CPB];                   // parity-dbuf partials

    // ---- one-time: weight slice -> registers, packed f16x2 --------------
    // wgt[q][m] covers gate-col (4l+q), k = {96w+2m, 96w+2m+1};
    // k<256 indexes Wi rows, k>=256 indexes Wh rows (fused operand order).
    uint32_t wgt[4][KL2];
    #pragma unroll
    for (int q = 0; q < 4; ++q) {
        const int c    = 4 * l + q;                       // local gate-col
        const int gcol = (c >> 6) * HDIM + s * HCB + (c & 63);
        #pragma unroll
        for (int m = 0; m < KL2; ++m) {
            const int k0 = KL * w + 2 * m;
            const int k1 = k0 + 1;
            const float f0 = (k0 < DIN) ? Wi[(size_t)k0 * G4 + gcol]
                                        : Wh[(size_t)(k0 - DIN) * G4 + gcol];
            const float f1 = (k1 < DIN) ? Wi[(size_t)k1 * G4 + gcol]
                                        : Wh[(size_t)(k1 - DIN) * G4 + gcol];
            wgt[q][m] = pack_f16x2(f0, f1);
        }
    }

    // update-thread persistent state (wave 0, lane j owns h-col s*64+j)
    float c_st = 0.f, lc_st = 0.f, lh_st = 0.f;
    float b_i = 0.f, b_f = 0.f, b_g = 0.f, b_o = 0.f;
    if (tid < HCB) {
        const int col = s * HCB + tid;
        b_i = bias[col];
        b_f = bias[HDIM + col];
        b_g = bias[2 * HDIM + col];
        b_o = bias[3 * HDIM + col];
    }
    const int len_b = lens[b];

    const float* xb = x + (size_t)b * TLEN * DIN;
    float* ys = out + 2 * BATCH * HDIM;   // out = [lc | lh | ys]

    // staging role for this lane: pair p=l of wave w's chunk (l<48 only)
    const int  k0     = KL * w + 2 * l;          // first k of this lane's pair
    const bool is_stg = (l < KL2);
    const bool is_x   = is_stg && (k0 < DIN);    // x pair: normal cached load
    const bool is_h   = is_stg && (k0 >= DIN);   // h pair: tagged-word poll

    // x prefetch one step ahead: keeps wave 0's HBM latency off the
    // publish->poll critical path (it computes x-dot right after update).
    float2 xx_cur = make_float2(0.f, 0.f);
    if (is_x) xx_cur = *(const float2*)(xb + k0);           // t = 0

    for (int t = 0; t < TLEN; ++t) {
        // ---- stage own chunk ------------------------------------------
        if (is_x) {
            u_lds[w][l] = pack_f16x2(xx_cur.x, xx_cur.y);
        } else if (is_h) {
            // poll both tagged words of the pair with one u64 atomic load;
            // tag==t means h_t payload is valid (parity t&1 holds tag t).
            const uint64_t* src = (const uint64_t*)
                (hT + (((size_t)(t & 1) * BATCH + b) * HDIM + (k0 - DIN)));
            const uint32_t tag = (uint32_t)t;
            uint64_t v;
            for (;;) {
                v = __hip_atomic_load(src, __ATOMIC_RELAXED,
                                      __HIP_MEMORY_SCOPE_AGENT);
                const uint32_t lo_tag = (uint32_t)(v >> 16) & 0xFFFFu;
                const uint32_t hi_tag = (uint32_t)(v >> 48);
                if ((lo_tag == tag) && (hi_tag == tag)) break;
            }
            // pack the two f16 payloads: bits[15:0] and bits[47:32]
            u_lds[w][l] = (uint32_t)(v & 0xFFFFu) |
                          (uint32_t)((v >> 16) & 0xFFFF0000u);
        }
        // issue next step's x load now; consumed next iteration
        if (is_x && (t + 1 < TLEN))
            xx_cur = *(const float2*)(xb + (size_t)(t + 1) * DIN + k0);

        // ---- dot phase: 4 gate-cols per lane, wave's 96-k chunk ---------
        float a0 = 0.f, a1 = 0.f, a2 = 0.f, a3 = 0.f;
        const uint4* uv = (const uint4*)&u_lds[w][0];
        #pragma unroll
        for (int m4 = 0; m4 < KL2 / 4; ++m4) {
            const uint4 uu = uv[m4];   // broadcast ds_read_b128
            a0 = dot2f(wgt[0][4 * m4 + 0], uu.x, a0);
            a0 = dot2f(wgt[0][4 * m4 + 1], uu.y, a0);
            a0 = dot2f(wgt[0][4 * m4 + 2], uu.z, a0);
            a0 = dot2f(wgt[0][4 * m4 + 3], uu.w, a0);
            a1 = dot2f(wgt[1][4 * m4 + 0], uu.x, a1);
            a1 = dot2f(wgt[1][4 * m4 + 1], uu.y, a1);
            a1 = dot2f(wgt[1][4 * m4 + 2], uu.z, a1);
            a1 = dot2f(wgt[1][4 * m4 + 3], uu.w, a1);
            a2 = dot2f(wgt[2][4 * m4 + 0], uu.x, a2);
            a2 = dot2f(wgt[2][4 * m4 + 1], uu.y, a2);
            a2 = dot2f(wgt[2][4 * m4 + 2], uu.z, a2);
            a2 = dot2f(wgt[2][4 * m4 + 3], uu.w, a2);
            a3 = dot2f(wgt[3][4 * m4 + 0], uu.x, a3);
            a3 = dot2f(wgt[3][4 * m4 + 1], uu.y, a3);
            a3 = dot2f(wgt[3][4 * m4 + 2], uu.z, a3);
            a3 = dot2f(wgt[3][4 * m4 + 3], uu.w, a3);
        }
        float4 av;
        av.x = a0; av.y = a1; av.z = a2; av.w = a3;
        *(float4*)&gp[t & 1][w][4 * l] = av;

        __syncthreads();   // the ONLY barrier per step

        // ---- update phase: wave 0 reduces 8 k-chunks, applies gates -----
        if (tid < HCB) {
            float si = b_i, sf = b_f, sg = b_g, so = b_o;
            #pragma unroll
            for (int ww = 0; ww < NWAVE; ++ww) {
                si += gp[t & 1][ww][tid];
                sf += gp[t & 1][ww][HCB + tid];
                sg += gp[t & 1][ww][2 * HCB + tid];
                so += gp[t & 1][ww][3 * HCB + tid];
            }
            const float ig = sigmoidf_(si);
            const float fg = sigmoidf_(sf);
            const float gg = tanhf_(sg);
            const float og = sigmoidf_(so);
            const float cn = fg * c_st + ig * gg;
            const float hn = og * tanhf_(cn);
            c_st = cn;
            if (t < len_b) { lc_st = cn; lh_st = hn; }
            // publish tagged h_{t+1} word to the other parity buffer; the
            // 32-bit store is atomic so tag+payload can never tear, and no
            // fence/flag is needed -- the tag IS the flag.
            const _Float16 hf = (_Float16)hn;
            const uint32_t word = ((uint32_t)(t + 1) << 16) |
                                  (uint32_t)__builtin_bit_cast(uint16_t, hf);
            __hip_atomic_store(
                &hT[((size_t)((t + 1) & 1) * BATCH + b) * HDIM + s * HCB + tid],
                word, __ATOMIC_RELAXED, __HIP_MEMORY_SCOPE_AGENT);
            // ys output (fp32, unmasked like the reference scan)
            ys[((size_t)b * TLEN + t) * HDIM + s * HCB + tid] = hn;
        }
        // no second barrier: gp parity double-buffer covers the one-step
        // overlap, and the tagged-word dependency chain covers step t+2.
    }

    // latched carry outputs
    if (tid < HCB) {
        out[(size_t)b * HDIM + s * HCB + tid] = lc_st;
        out[BATCH * HDIM + (size_t)b * HDIM + s * HCB + tid] = lh_st;
    }
}

extern "C" void kernel_launch(void* const* d_in, const int* in_sizes, int n_in,
                              void* d_out, int out_size, void* d_ws, size_t ws_size,
                              hipStream_t stream)
{
    const float* x    = (const float*)d_in[0];   // [32,2048,256] f32
    const int*   lens = (const int*)d_in[1];     // [32] i32
    const float* Wi   = (const float*)d_in[2];   // [256,2048] f32
    const float* Wh   = (const float*)d_in[3];   // [512,2048] f32
    const float* bias = (const float*)d_in[4];   // [2048] f32
    float* out = (float*)d_out;                  // [lc(16384) | lh(16384) | ys]

    uint32_t* hT = (uint32_t*)d_ws;              // [2][32][512] tagged u32
    // Zero BOTH parities: parity 0 = (tag=0, h=0) satisfies t=0 polls
    // immediately (h_0 = 0); parity 1 = tag 0, which matches no polled tag
    // (polled tags in parity 1 are odd >= 1), so readers spin until written.
    // Safe even without the harness's 0xAA re-poison.
    const size_t init_bytes = (size_t)2 * BATCH * HDIM * sizeof(uint32_t);
    hipMemsetAsync(d_ws, 0, init_bytes, stream);

    hipLaunchKernelGGL(lstm_persist, dim3(NBLK), dim3(NTHR), 0, stream,
                       x, lens, Wi, Wh, bias, out, hT);
}